// Round 1
// 768.226 us; speedup vs baseline: 1.6329x; 1.6329x over previous
//
#include <hip/hip_runtime.h>

typedef unsigned short u16;
typedef unsigned int u32;
typedef __attribute__((ext_vector_type(8))) __bf16 bf16x8;
typedef __attribute__((ext_vector_type(4))) float f32x4;
typedef __attribute__((ext_vector_type(4))) u32 u32x4;

#define MDIM 4096
#define KDIM 4096
#define NDIM 6144
#define SDIM 2048
#define KC   (KDIM / 32)   // 128 k-chunks of 32

__device__ __forceinline__ u32 asu(float f) { return __float_as_uint(f); }

// async global->LDS, 16B per lane; global addr per-lane, LDS dest wave-uniform
__device__ __forceinline__ void gld16(const void* g, void* l) {
    __builtin_amdgcn_global_load_lds(
        (const __attribute__((address_space(1))) u32*)g,
        (__attribute__((address_space(3))) u32*)l, 16, 0, 0);
}

// pack two fp32's truncated-bf16 halves: low = hi16(a), high = hi16(b)
__device__ __forceinline__ u32 pk(float a, float b) {
    return (asu(a) >> 16) | (asu(b) & 0xffff0000u);
}

// ---------------------------------------------------------------------------
// Kernel 1: transpose W fp32 (K x N, n-contig) -> Whl: per (n, kchunk) a 128B
// record { 32 x hi bf16 | 32 x lo bf16 } with k contiguous inside each half.
// hi = trunc_bf16(w), lo = trunc_bf16(w - hi).
// ---------------------------------------------------------------------------
__global__ __launch_bounds__(256) void transpose_w(const float* __restrict__ W,
                                                   u32* __restrict__ Whl) {
    __shared__ u32 wh[64][33];
    __shared__ u32 wl[64][33];
    const int t = threadIdx.x;
    const int n0 = blockIdx.x * 64;
    const int k0 = blockIdx.y * 64;
#pragma unroll
    for (int r = 0; r < 4; ++r) {
        int bid = t + r * 256;           // 0..1023 : 32x32 2x2-blocks
        int nb = bid & 31;
        int kb = bid >> 5;
        const float* p0 = W + (size_t)(k0 + 2 * kb) * NDIM + n0 + 2 * nb;
        float2 w0 = *(const float2*)p0;          // k   : n, n+1
        float2 w1 = *(const float2*)(p0 + NDIM); // k+1 : n, n+1
        float h00 = __uint_as_float(asu(w0.x) & 0xffff0000u);
        float h01 = __uint_as_float(asu(w0.y) & 0xffff0000u);
        float h10 = __uint_as_float(asu(w1.x) & 0xffff0000u);
        float h11 = __uint_as_float(asu(w1.y) & 0xffff0000u);
        // element (n, kpair): low16 = k, high16 = k+1
        wh[2 * nb][kb]     = pk(w0.x, w1.x);
        wh[2 * nb + 1][kb] = pk(w0.y, w1.y);
        wl[2 * nb][kb]     = pk(w0.x - h00, w1.x - h10);
        wl[2 * nb + 1][kb] = pk(w0.y - h01, w1.y - h11);
    }
    __syncthreads();
#pragma unroll
    for (int r = 0; r < 2; ++r) {
        int v = t + r * 256;             // 0..511
        int nl = v >> 3;                 // 0..63
        int kw = (v & 7) * 4;            // word index 0..28 within 64-k span
        int c  = (k0 >> 5) + (kw >> 4);  // global k-chunk
        int ww = kw & 15;                // word within chunk's hi section
        size_t o = ((size_t)(n0 + nl) * KC + c) * 32 + ww;
        *(uint4*)(Whl + o)      = make_uint4(wh[nl][kw], wh[nl][kw + 1],
                                             wh[nl][kw + 2], wh[nl][kw + 3]);
        *(uint4*)(Whl + o + 16) = make_uint4(wl[nl][kw], wl[nl][kw + 1],
                                             wl[nl][kw + 2], wl[nl][kw + 3]);
    }
}

// ---------------------------------------------------------------------------
// Kernel 2: fused split-bf16 GEMM + LLTM epilogue.
// Block = 128 M x 64 S-cols, all three gate chunks -> in-register epilogue.
// Double-buffered LDS; next k-chunk staged (10 gld16) BEFORE computing the
// current one, single vmcnt(0)+barrier per iter -> load latency hides under
// 72 MFMA of compute.
// A: fp32 staged via gld16 (XOR-swizzled 16B granules), split hi/lo at read.
// B: pre-split bf16 {hi|lo} records, staged with pre-swizzled global source
//    (granule ^= row&7) so swizzled ds_read_b128 is bank-conflict-free.
// ---------------------------------------------------------------------------
__global__ __launch_bounds__(256, 2) void gemm_lltm(const u32* __restrict__ Whl,
                                                    const float* __restrict__ oldh,
                                                    const float* __restrict__ inp,
                                                    const float* __restrict__ bias,
                                                    const float* __restrict__ oldc,
                                                    float* __restrict__ out) {
    __shared__ float Af[2][128 * 32];    // fp32 A tile, row stride 32 floats
    __shared__ u16  Bs[2][192 * 64];     // B tile: row = {32 hi | 32 lo} u16
    const int t = threadIdx.x;
    const int lane = t & 63;
    const int wv = t >> 6;
    const int wm = wv >> 1;              // wave M-half (64 rows)
    const int wn = wv & 1;               // wave S-half (32 cols)
    const int row0 = blockIdx.y * 128;
    const int col0 = blockIdx.x * 64;

    f32x4 acc[3][4][2];
#pragma unroll
    for (int g = 0; g < 3; ++g)
#pragma unroll
        for (int i = 0; i < 4; ++i)
#pragma unroll
            for (int j = 0; j < 2; ++j)
                acc[g][i][j] = (f32x4){0.f, 0.f, 0.f, 0.f};

    const int sr8 = lane >> 3;                   // staging row-in-group
    const int lg  = (lane & 7) ^ sr8;            // swizzled granule 0..7
    const int sg4 = lg * 4;                      // A swizzled float offset

    // A staging source offsets (element index into oldh/inp row space)
    size_t aOff[4];
#pragma unroll
    for (int i = 0; i < 4; ++i)
        aOff[i] = (size_t)(row0 + wv * 32 + i * 8 + sr8) * SDIM + sg4;

    // B staging source pointers (per-lane, pre-swizzled granule)
    const u32* bSrc[6];
#pragma unroll
    for (int p = 0; p < 6; ++p) {
        int r = wv * 48 + p * 8 + sr8;           // tile row 0..191
        int n = (r >> 6) * SDIM + col0 + (r & 63);
        bSrc[p] = Whl + (size_t)n * (KC * 32) + lg * 4;
    }

    const int lm = lane & 15;
    const int q  = lane >> 4;
    const int sw = lm & 7;                       // == (frag row) & 7
    const int slotHi = q ^ sw;                   // B hi granule LDS slot

    // prologue: stage chunk 0 into buffer 0
    {
#pragma unroll
        for (int i = 0; i < 4; ++i)
            gld16(oldh + aOff[i], &Af[0][(wv * 32 + i * 8) * 32]);
#pragma unroll
        for (int p = 0; p < 6; ++p)
            gld16(bSrc[p], &Bs[0][(wv * 384 + p * 64) * 8]);
    }
    asm volatile("s_waitcnt vmcnt(0)" ::: "memory");
    __syncthreads();

    for (int c = 0; c < KC; ++c) {
        const int buf = c & 1;
        // stage chunk c+1 into the other buffer (latency hides under compute)
        if (c + 1 < KC) {
            const int kt = (c + 1) * 32;
            const float* Abase = (kt < SDIM) ? oldh : inp;
            const size_t kcol = (size_t)(kt & (SDIM - 1));
#pragma unroll
            for (int i = 0; i < 4; ++i)
                gld16(Abase + aOff[i] + kcol, &Af[buf ^ 1][(wv * 32 + i * 8) * 32]);
#pragma unroll
            for (int p = 0; p < 6; ++p)
                gld16(bSrc[p] + (size_t)(c + 1) * 32,
                      &Bs[buf ^ 1][(wv * 384 + p * 64) * 8]);
        }

        // compute current buffer
        bf16x8 ah[4], al[4];
#pragma unroll
        for (int i = 0; i < 4; ++i) {
            int m = wm * 64 + i * 16 + lm;
            const float* rp = &Af[buf][m * 32];
            float4 fa = *(const float4*)(rp + (((2 * q) ^ sw) * 4));
            float4 fb = *(const float4*)(rp + (((2 * q + 1) ^ sw) * 4));
            ah[i] = __builtin_bit_cast(bf16x8, (u32x4){
                pk(fa.x, fa.y), pk(fa.z, fa.w), pk(fb.x, fb.y), pk(fb.z, fb.w)});
            float4 ga, gb;
            ga.x = fa.x - __uint_as_float(asu(fa.x) & 0xffff0000u);
            ga.y = fa.y - __uint_as_float(asu(fa.y) & 0xffff0000u);
            ga.z = fa.z - __uint_as_float(asu(fa.z) & 0xffff0000u);
            ga.w = fa.w - __uint_as_float(asu(fa.w) & 0xffff0000u);
            gb.x = fb.x - __uint_as_float(asu(fb.x) & 0xffff0000u);
            gb.y = fb.y - __uint_as_float(asu(fb.y) & 0xffff0000u);
            gb.z = fb.z - __uint_as_float(asu(fb.z) & 0xffff0000u);
            gb.w = fb.w - __uint_as_float(asu(fb.w) & 0xffff0000u);
            al[i] = __builtin_bit_cast(bf16x8, (u32x4){
                pk(ga.x, ga.y), pk(ga.z, ga.w), pk(gb.x, gb.y), pk(gb.z, gb.w)});
        }
#pragma unroll
        for (int g = 0; g < 3; ++g) {
#pragma unroll
            for (int j = 0; j < 2; ++j) {
                int r = g * 64 + wn * 32 + j * 16 + lm;
                const u16* bp = &Bs[buf][r * 64];
                bf16x8 bh = *(const bf16x8*)(bp + slotHi * 8);
                bf16x8 bl = *(const bf16x8*)(bp + (slotHi ^ 4) * 8);
#pragma unroll
                for (int i = 0; i < 4; ++i)
                    acc[g][i][j] = __builtin_amdgcn_mfma_f32_16x16x32_bf16(
                        ah[i], bh, acc[g][i][j], 0, 0, 0);
#pragma unroll
                for (int i = 0; i < 4; ++i)
                    acc[g][i][j] = __builtin_amdgcn_mfma_f32_16x16x32_bf16(
                        al[i], bh, acc[g][i][j], 0, 0, 0);
#pragma unroll
                for (int i = 0; i < 4; ++i)
                    acc[g][i][j] = __builtin_amdgcn_mfma_f32_16x16x32_bf16(
                        ah[i], bl, acc[g][i][j], 0, 0, 0);
            }
        }
        asm volatile("s_waitcnt vmcnt(0)" ::: "memory");
        __syncthreads();
    }

    // fused LLTM epilogue. C/D layout: col = lane&15, row = (lane>>4)*4 + reg.
    const int rq = q * 4;
#pragma unroll
    for (int j = 0; j < 2; ++j) {
        int scol = col0 + wn * 32 + j * 16 + lm;
        float b0v = bias[scol];
        float b1v = bias[SDIM + scol];
        float b2v = bias[2 * SDIM + scol];
#pragma unroll
        for (int i = 0; i < 4; ++i) {
#pragma unroll
            for (int r = 0; r < 4; ++r) {
                int row = row0 + wm * 64 + i * 16 + rq + r;
                float x0 = acc[0][i][j][r] + b0v;
                float x1 = acc[1][i][j][r] + b1v;
                float x2 = acc[2][i][j][r] + b2v;
                float ig = 1.f / (1.f + __expf(-x0));
                float og = 1.f / (1.f + __expf(-x1));
                float el = x2 > 0.f ? x2 : (__expf(x2) - 1.f);
                float nc = oldc[(size_t)row * SDIM + scol] + el * ig;
                float nh = tanhf(nc) * og;
                out[(size_t)row * SDIM + scol] = nh;
                out[(size_t)MDIM * SDIM + (size_t)row * SDIM + scol] = nc;
            }
        }
    }
}

// ---------------------------------------------------------------------------
extern "C" void kernel_launch(void* const* d_in, const int* in_sizes, int n_in,
                              void* d_out, int out_size, void* d_ws, size_t ws_size,
                              hipStream_t stream) {
    const float* W    = (const float*)d_in[0];   // (4096, 6144) fp32
    const float* bias = (const float*)d_in[1];   // (6144,) fp32
    const float* inp  = (const float*)d_in[2];   // (4096, 2048) fp32
    const float* oldh = (const float*)d_in[3];   // (4096, 2048) fp32
    const float* oldc = (const float*)d_in[4];   // (4096, 2048) fp32

    u32* Whl = (u32*)d_ws;                       // 96 MB {hi|lo} records

    transpose_w<<<dim3(NDIM / 64, KDIM / 64), 256, 0, stream>>>(W, Whl);
    gemm_lltm<<<dim3(SDIM / 64, MDIM / 128), 256, 0, stream>>>(Whl, oldh, inp,
                                                               bias, oldc,
                                                               (float*)d_out);
}